// Round 1
// baseline (2495.819 us; speedup 1.0000x reference)
//
#include <hip/hip_runtime.h>
#include <hip/hip_bf16.h>

// Problem constants (from reference)
#define N_DIM   128   // NODE_DIM
#define MUL0    128
#define MUL1    64
#define MUL2    32
#define NIRR    224   // NUM_IRREPS
#define SPHD    480   // SPH_DIM
#define HID     352   // HIDDEN
#define NBASIS  20
#define EPSV    1e-5f

__device__ __forceinline__ float wave_sum(float v) {
  #pragma unroll
  for (int o = 32; o > 0; o >>= 1) v += __shfl_xor(v, o, 64);
  return v;
}

// ---------------------------------------------------------------------------
// Kernel 1: per-node LayerNorm (scalar) + O3 layer norm (spherical).
// Writes results directly into d_out (they are the scatter-add base values).
// One 64-lane wave per node.
// ---------------------------------------------------------------------------
__global__ __launch_bounds__(64) void node_norm_kernel(
    const float* __restrict__ x_scalar, const float* __restrict__ x_sph,
    const float* __restrict__ ln_g, const float* __restrict__ ln_b,
    const float* __restrict__ o3_w, const float* __restrict__ o3_b,
    float* __restrict__ out_scal, float* __restrict__ out_sph) {
  const int n = blockIdx.x;
  const int l = threadIdx.x;

  // ---- scalar LayerNorm over 128 dims ----
  const float* xs = x_scalar + (size_t)n * N_DIM;
  float a0 = xs[l], a1 = xs[l + 64];
  float mu = wave_sum(a0 + a1) * (1.f / 128.f);
  float d0 = a0 - mu, d1 = a1 - mu;
  float var = wave_sum(d0 * d0 + d1 * d1) * (1.f / 128.f);
  float sc = rsqrtf(var + EPSV);
  float* os = out_scal + (size_t)n * N_DIM;
  os[l]      = d0 * sc * ln_g[l]      + ln_b[l];
  os[l + 64] = d1 * sc * ln_g[l + 64] + ln_b[l + 64];

  // ---- O3 norm: scalar part (128) ----
  const float* xp = x_sph + (size_t)n * SPHD;
  float s0 = xp[l], s1 = xp[l + 64];
  mu = wave_sum(s0 + s1) * (1.f / 128.f);
  d0 = s0 - mu; d1 = s1 - mu;
  var = wave_sum(d0 * d0 + d1 * d1) * (1.f / 128.f);
  sc = rsqrtf(var + EPSV);
  float* op = out_sph + (size_t)n * SPHD;
  op[l]      = d0 * sc * o3_w[l]      + o3_b[l];
  op[l + 64] = d1 * sc * o3_w[l + 64] + o3_b[l + 64];

  // ---- O3 norm: vector part (64 muls x 3 = 192) ----
  float v0 = xp[128 + l], v1 = xp[128 + 64 + l], v2 = xp[128 + 128 + l];
  float nv = wave_sum(v0 * v0 + v1 * v1 + v2 * v2) * (1.f / 192.f);
  sc = rsqrtf(nv + EPSV);
  op[128 + l]       = v0 * sc * o3_w[MUL0 + (l) / 3];
  op[128 + 64 + l]  = v1 * sc * o3_w[MUL0 + (l + 64) / 3];
  op[128 + 128 + l] = v2 * sc * o3_w[MUL0 + (l + 128) / 3];

  // ---- O3 norm: tensor part (32 muls x 5 = 160) ----
  float t0 = xp[320 + l], t1 = xp[320 + 64 + l];
  float t2 = (l < 32) ? xp[320 + 128 + l] : 0.f;
  float nt = wave_sum(t0 * t0 + t1 * t1 + t2 * t2) * (1.f / 160.f);
  sc = rsqrtf(nt + EPSV);
  op[320 + l]      = t0 * sc * o3_w[MUL0 + MUL1 + (l) / 5];
  op[320 + 64 + l] = t1 * sc * o3_w[MUL0 + MUL1 + (l + 64) / 5];
  if (l < 32) op[320 + 128 + l] = t2 * sc * o3_w[MUL0 + MUL1 + (l + 128) / 5];
}

// ---------------------------------------------------------------------------
// Kernel 2/3: tiled fp32 SGEMM, C = act(A @ B + bias).
// BM=64, BN=64, BK=16, 256 threads, 4x4 micro-tile, float4 LDS reads.
// ---------------------------------------------------------------------------
template <bool SILU>
__global__ __launch_bounds__(256) void sgemm_kernel(
    const float* __restrict__ A, const float* __restrict__ B,
    const float* __restrict__ bias, float* __restrict__ C,
    int M, int N, int K) {
  __shared__ __align__(16) float As[16][68];
  __shared__ __align__(16) float Bs[16][68];
  const int tid = threadIdx.x;
  const int bm = blockIdx.x * 64, bn = blockIdx.y * 64;
  const int tr = (tid >> 4) << 2;   // micro-tile row base
  const int tc = (tid & 15) << 2;   // micro-tile col base
  const int ar = tid >> 2;          // A-load row 0..63
  const int ak = (tid & 3) << 2;    // A-load k 0,4,8,12
  const int bk = tid >> 4;          // B-load k 0..15
  const int bc = (tid & 15) << 2;   // B-load col

  float acc[4][4] = {};
  for (int k0 = 0; k0 < K; k0 += 16) {
    int gr = bm + ar;
    if (gr < M) {
      float4 a = *(const float4*)(A + (size_t)gr * K + k0 + ak);
      As[ak][ar] = a.x; As[ak + 1][ar] = a.y; As[ak + 2][ar] = a.z; As[ak + 3][ar] = a.w;
    } else {
      As[ak][ar] = 0.f; As[ak + 1][ar] = 0.f; As[ak + 2][ar] = 0.f; As[ak + 3][ar] = 0.f;
    }
    int gk = k0 + bk, gc = bn + bc;
    if (gc + 3 < N) {
      float4 b = *(const float4*)(B + (size_t)gk * N + gc);
      Bs[bk][bc] = b.x; Bs[bk][bc + 1] = b.y; Bs[bk][bc + 2] = b.z; Bs[bk][bc + 3] = b.w;
    } else {
      #pragma unroll
      for (int i = 0; i < 4; ++i)
        Bs[bk][bc + i] = (gc + i < N) ? B[(size_t)gk * N + gc + i] : 0.f;
    }
    __syncthreads();
    #pragma unroll
    for (int k = 0; k < 16; ++k) {
      float4 av = *(const float4*)&As[k][tr];
      float4 bv = *(const float4*)&Bs[k][tc];
      float a4[4] = {av.x, av.y, av.z, av.w};
      float b4[4] = {bv.x, bv.y, bv.z, bv.w};
      #pragma unroll
      for (int i = 0; i < 4; ++i)
        #pragma unroll
        for (int j = 0; j < 4; ++j) acc[i][j] += a4[i] * b4[j];
    }
    __syncthreads();
  }
  #pragma unroll
  for (int i = 0; i < 4; ++i) {
    int r = bm + tr + i;
    if (r >= M) continue;
    #pragma unroll
    for (int j = 0; j < 4; ++j) {
      int c = bn + tc + j;
      if (c >= N) continue;
      float v = acc[i][j] + bias[c];
      if (SILU) v = v / (1.f + __expf(-v));
      C[(size_t)r * N + c] = v;
    }
  }
}

// ---------------------------------------------------------------------------
// Kernel 4: per-edge filter + spherical-harmonic gating + atomic scatter.
// Wrbf (20x352 = 28.2 KB) staged in LDS once per block; 16 edges per block.
// ---------------------------------------------------------------------------
#define EDGES_PER_BLOCK 16

__global__ __launch_bounds__(256) void edge_kernel(
    const float* __restrict__ rbf, const float* __restrict__ vec,
    const float* __restrict__ Wrbf, const float* __restrict__ scalar_out,
    const int* __restrict__ edge_index,
    float* __restrict__ out_scal, float* __restrict__ out_sph, int n_edges) {
  __shared__ float Ws[NBASIS * HID];
  for (int i = threadIdx.x; i < NBASIS * HID; i += 256) Ws[i] = Wrbf[i];
  __syncthreads();

  const int e0 = blockIdx.x * EDGES_PER_BLOCK;
  const int e1 = min(e0 + EDGES_PER_BLOCK, n_edges);
  for (int e = e0; e < e1; ++e) {
    const int dst = edge_index[e];
    const int src = edge_index[n_edges + e];
    // spherical harmonics of normalized edge vector (computed redundantly per thread)
    float vx = vec[(size_t)e * 3], vy = vec[(size_t)e * 3 + 1], vz = vec[(size_t)e * 3 + 2];
    float rn = rsqrtf(vx * vx + vy * vy + vz * vz);
    float x = vx * rn, y = vy * rn, z = vz * rn;
    const float S3 = 1.7320508075688772f;
    const float S15 = 3.872983346207417f;
    const float S5 = 2.2360679774997896f;
    float sh1x = S3 * x, sh1y = S3 * y, sh1z = S3 * z;
    float sh20 = S15 * x * z;
    float sh21 = S15 * x * y;
    float sh22 = S5 * (y * y - 0.5f * (x * x + z * z));
    float sh23 = S15 * y * z;
    float sh24 = 0.5f * S15 * (z * z - x * x);

    float rb[NBASIS];
    #pragma unroll
    for (int k = 0; k < NBASIS; ++k) rb[k] = rbf[(size_t)e * NBASIS + k];  // wave-broadcast loads

    const float* so = scalar_out + (size_t)src * HID;
    float* sphd = out_sph + (size_t)dst * SPHD;
    float* scld = out_scal + (size_t)dst * N_DIM;

    for (int c = threadIdx.x; c < HID; c += 256) {
      float fw = 0.f;
      #pragma unroll
      for (int k = 0; k < NBASIS; ++k) fw += rb[k] * Ws[k * HID + c];
      float f = so[c] * fw;
      if (c < MUL0) {
        atomicAdd(&sphd[c], f);
      } else if (c < MUL0 + MUL1) {
        float* p = &sphd[128 + 3 * (c - MUL0)];
        atomicAdd(p, f * sh1x); atomicAdd(p + 1, f * sh1y); atomicAdd(p + 2, f * sh1z);
      } else if (c < NIRR) {
        float* p = &sphd[320 + 5 * (c - MUL0 - MUL1)];
        atomicAdd(p, f * sh20); atomicAdd(p + 1, f * sh21); atomicAdd(p + 2, f * sh22);
        atomicAdd(p + 3, f * sh23); atomicAdd(p + 4, f * sh24);
      } else {
        atomicAdd(&scld[c - NIRR], f);
      }
    }
  }
}

// ---------------------------------------------------------------------------
extern "C" void kernel_launch(void* const* d_in, const int* in_sizes, int n_in,
                              void* d_out, int out_size, void* d_ws, size_t ws_size,
                              hipStream_t stream) {
  const float* x_scalar = (const float*)d_in[0];
  const float* x_sph    = (const float*)d_in[1];
  const float* rbf      = (const float*)d_in[2];
  const float* vec      = (const float*)d_in[3];
  const float* W1       = (const float*)d_in[4];
  const float* b1       = (const float*)d_in[5];
  const float* W2       = (const float*)d_in[6];
  const float* b2       = (const float*)d_in[7];
  const float* Wrbf     = (const float*)d_in[8];
  const float* ln_g     = (const float*)d_in[9];
  const float* ln_b     = (const float*)d_in[10];
  const float* o3_w     = (const float*)d_in[11];
  const float* o3_b     = (const float*)d_in[12];
  const int*   edge_idx = (const int*)d_in[13];

  const int n_nodes = in_sizes[0] / N_DIM;   // 50000
  const int n_edges = in_sizes[2] / NBASIS;  // 400000

  float* out_scal = (float*)d_out;                          // [n_nodes,128]
  float* out_sph  = out_scal + (size_t)n_nodes * N_DIM;     // [n_nodes,480]

  float* ws_h  = (float*)d_ws;                              // [n_nodes,128]
  float* ws_so = ws_h + (size_t)n_nodes * N_DIM;            // [n_nodes,352]

  // 1) node norms -> d_out (scatter base)
  node_norm_kernel<<<n_nodes, 64, 0, stream>>>(
      x_scalar, x_sph, ln_g, ln_b, o3_w, o3_b, out_scal, out_sph);

  // 2) h = silu(scalar_in @ W1 + b1)
  dim3 g1((n_nodes + 63) / 64, (N_DIM + 63) / 64);
  sgemm_kernel<true><<<g1, 256, 0, stream>>>(out_scal, W1, b1, ws_h, n_nodes, N_DIM, N_DIM);

  // 3) scalar_out = h @ W2 + b2
  dim3 g2((n_nodes + 63) / 64, (HID + 63) / 64);
  sgemm_kernel<false><<<g2, 256, 0, stream>>>(ws_h, W2, b2, ws_so, n_nodes, HID, N_DIM);

  // 4) edge messages + atomic scatter into d_out
  edge_kernel<<<(n_edges + EDGES_PER_BLOCK - 1) / EDGES_PER_BLOCK, 256, 0, stream>>>(
      rbf, vec, Wrbf, ws_so, edge_idx, out_scal, out_sph, n_edges);
}

// Round 2
// 932.300 us; speedup vs baseline: 2.6771x; 2.6771x over previous
//
#include <hip/hip_runtime.h>
#include <hip/hip_bf16.h>

// Problem constants (from reference)
#define N_DIM   128   // NODE_DIM
#define MUL0    128
#define MUL1    64
#define MUL2    32
#define NIRR    224   // NUM_IRREPS
#define SPHD    480   // SPH_DIM
#define HID     352   // HIDDEN
#define NBASIS  20
#define EPSV    1e-5f

__device__ __forceinline__ float wave_sum(float v) {
  #pragma unroll
  for (int o = 32; o > 0; o >>= 1) v += __shfl_xor(v, o, 64);
  return v;
}

// ---------------------------------------------------------------------------
// Kernel 1: per-node LayerNorm (scalar) + O3 layer norm (spherical).
// Writes results directly into d_out (they are the scatter-add base values).
// One 64-lane wave per node.
// ---------------------------------------------------------------------------
__global__ __launch_bounds__(64) void node_norm_kernel(
    const float* __restrict__ x_scalar, const float* __restrict__ x_sph,
    const float* __restrict__ ln_g, const float* __restrict__ ln_b,
    const float* __restrict__ o3_w, const float* __restrict__ o3_b,
    float* __restrict__ out_scal, float* __restrict__ out_sph) {
  const int n = blockIdx.x;
  const int l = threadIdx.x;

  // ---- scalar LayerNorm over 128 dims ----
  const float* xs = x_scalar + (size_t)n * N_DIM;
  float a0 = xs[l], a1 = xs[l + 64];
  float mu = wave_sum(a0 + a1) * (1.f / 128.f);
  float d0 = a0 - mu, d1 = a1 - mu;
  float var = wave_sum(d0 * d0 + d1 * d1) * (1.f / 128.f);
  float sc = rsqrtf(var + EPSV);
  float* os = out_scal + (size_t)n * N_DIM;
  os[l]      = d0 * sc * ln_g[l]      + ln_b[l];
  os[l + 64] = d1 * sc * ln_g[l + 64] + ln_b[l + 64];

  // ---- O3 norm: scalar part (128) ----
  const float* xp = x_sph + (size_t)n * SPHD;
  float s0 = xp[l], s1 = xp[l + 64];
  mu = wave_sum(s0 + s1) * (1.f / 128.f);
  d0 = s0 - mu; d1 = s1 - mu;
  var = wave_sum(d0 * d0 + d1 * d1) * (1.f / 128.f);
  sc = rsqrtf(var + EPSV);
  float* op = out_sph + (size_t)n * SPHD;
  op[l]      = d0 * sc * o3_w[l]      + o3_b[l];
  op[l + 64] = d1 * sc * o3_w[l + 64] + o3_b[l + 64];

  // ---- O3 norm: vector part (64 muls x 3 = 192) ----
  float v0 = xp[128 + l], v1 = xp[128 + 64 + l], v2 = xp[128 + 128 + l];
  float nv = wave_sum(v0 * v0 + v1 * v1 + v2 * v2) * (1.f / 192.f);
  sc = rsqrtf(nv + EPSV);
  op[128 + l]       = v0 * sc * o3_w[MUL0 + (l) / 3];
  op[128 + 64 + l]  = v1 * sc * o3_w[MUL0 + (l + 64) / 3];
  op[128 + 128 + l] = v2 * sc * o3_w[MUL0 + (l + 128) / 3];

  // ---- O3 norm: tensor part (32 muls x 5 = 160) ----
  float t0 = xp[320 + l], t1 = xp[320 + 64 + l];
  float t2 = (l < 32) ? xp[320 + 128 + l] : 0.f;
  float nt = wave_sum(t0 * t0 + t1 * t1 + t2 * t2) * (1.f / 160.f);
  sc = rsqrtf(nt + EPSV);
  op[320 + l]      = t0 * sc * o3_w[MUL0 + MUL1 + (l) / 5];
  op[320 + 64 + l] = t1 * sc * o3_w[MUL0 + MUL1 + (l + 64) / 5];
  if (l < 32) op[320 + 128 + l] = t2 * sc * o3_w[MUL0 + MUL1 + (l + 128) / 5];
}

// ---------------------------------------------------------------------------
// Kernel 2/3: tiled fp32 SGEMM, C = act(A @ B + bias).
// BM=64, BN=64, BK=16, 256 threads, 4x4 micro-tile, float4 LDS reads.
// ---------------------------------------------------------------------------
template <bool SILU>
__global__ __launch_bounds__(256) void sgemm_kernel(
    const float* __restrict__ A, const float* __restrict__ B,
    const float* __restrict__ bias, float* __restrict__ C,
    int M, int N, int K) {
  __shared__ __align__(16) float As[16][68];
  __shared__ __align__(16) float Bs[16][68];
  const int tid = threadIdx.x;
  const int bm = blockIdx.x * 64, bn = blockIdx.y * 64;
  const int tr = (tid >> 4) << 2;
  const int tc = (tid & 15) << 2;
  const int ar = tid >> 2;
  const int ak = (tid & 3) << 2;
  const int bk = tid >> 4;
  const int bc = (tid & 15) << 2;

  float acc[4][4] = {};
  for (int k0 = 0; k0 < K; k0 += 16) {
    int gr = bm + ar;
    if (gr < M) {
      float4 a = *(const float4*)(A + (size_t)gr * K + k0 + ak);
      As[ak][ar] = a.x; As[ak + 1][ar] = a.y; As[ak + 2][ar] = a.z; As[ak + 3][ar] = a.w;
    } else {
      As[ak][ar] = 0.f; As[ak + 1][ar] = 0.f; As[ak + 2][ar] = 0.f; As[ak + 3][ar] = 0.f;
    }
    int gk = k0 + bk, gc = bn + bc;
    if (gc + 3 < N) {
      float4 b = *(const float4*)(B + (size_t)gk * N + gc);
      Bs[bk][bc] = b.x; Bs[bk][bc + 1] = b.y; Bs[bk][bc + 2] = b.z; Bs[bk][bc + 3] = b.w;
    } else {
      #pragma unroll
      for (int i = 0; i < 4; ++i)
        Bs[bk][bc + i] = (gc + i < N) ? B[(size_t)gk * N + gc + i] : 0.f;
    }
    __syncthreads();
    #pragma unroll
    for (int k = 0; k < 16; ++k) {
      float4 av = *(const float4*)&As[k][tr];
      float4 bv = *(const float4*)&Bs[k][tc];
      float a4[4] = {av.x, av.y, av.z, av.w};
      float b4[4] = {bv.x, bv.y, bv.z, bv.w};
      #pragma unroll
      for (int i = 0; i < 4; ++i)
        #pragma unroll
        for (int j = 0; j < 4; ++j) acc[i][j] += a4[i] * b4[j];
    }
    __syncthreads();
  }
  #pragma unroll
  for (int i = 0; i < 4; ++i) {
    int r = bm + tr + i;
    if (r >= M) continue;
    #pragma unroll
    for (int j = 0; j < 4; ++j) {
      int c = bn + tc + j;
      if (c >= N) continue;
      float v = acc[i][j] + bias[c];
      if (SILU) v = v / (1.f + __expf(-v));
      C[(size_t)r * N + c] = v;
    }
  }
}

// ---------------------------------------------------------------------------
// CSR build: histogram of dst, exclusive scan, fill sorted-edge list.
// ---------------------------------------------------------------------------
__global__ void hist_kernel(const int* __restrict__ ei, int* __restrict__ deg,
                            int n_edges) {
  int e = blockIdx.x * blockDim.x + threadIdx.x;
  if (e < n_edges) atomicAdd(&deg[ei[e]], 1);
}

__global__ __launch_bounds__(1024) void scan_kernel(const int* __restrict__ deg,
                                                    int* __restrict__ offs, int n) {
  __shared__ int wsum[16];
  __shared__ int s_carry;
  const int tid = threadIdx.x;
  const int lane = tid & 63, wid = tid >> 6;
  if (tid == 0) s_carry = 0;
  __syncthreads();
  for (int base = 0; base < n; base += 1024) {
    int i = base + tid;
    int v = (i < n) ? deg[i] : 0;
    int s = v;  // inclusive wave scan
    #pragma unroll
    for (int o = 1; o < 64; o <<= 1) {
      int t = __shfl_up(s, o, 64);
      if (lane >= o) s += t;
    }
    if (lane == 63) wsum[wid] = s;
    __syncthreads();
    if (wid == 0) {
      int ws = (lane < 16) ? wsum[lane] : 0;
      #pragma unroll
      for (int o = 1; o < 16; o <<= 1) {
        int t = __shfl_up(ws, o, 64);
        if (lane >= o) ws += t;
      }
      if (lane < 16) wsum[lane] = ws;  // inclusive wave sums
    }
    __syncthreads();
    int wave_excl = (wid == 0) ? 0 : wsum[wid - 1];
    int carry = s_carry;
    if (i < n) offs[i] = carry + wave_excl + s - v;  // exclusive
    __syncthreads();
    if (tid == 0) s_carry = carry + wsum[15];
    __syncthreads();
  }
  if (tid == 0) offs[n] = s_carry;
}

__global__ void fill_kernel(const int* __restrict__ ei, const int* __restrict__ offs,
                            int* __restrict__ cursor, int* __restrict__ sorted,
                            int n_edges) {
  int e = blockIdx.x * blockDim.x + threadIdx.x;
  if (e < n_edges) {
    int d = ei[e];
    int p = atomicAdd(&cursor[d], 1);
    sorted[offs[d] + p] = e;
  }
}

// ---------------------------------------------------------------------------
// Gather kernel: one block per NPB nodes; thread t owns output elements
// j = t, t+256, t+512 (608 total per node: 480 sph + 128 scalar).
// Wrbf columns for a thread's outputs live in REGISTERS (reused over all
// edges/nodes) -> no LDS, no atomics; one plain += per output per node.
// ---------------------------------------------------------------------------
#define NPB 8
#define S3f  1.7320508075688772f
#define S15f 3.872983346207417f
#define S5f  2.2360679774997896f

__global__ __launch_bounds__(256) void gather_kernel(
    const float* __restrict__ rbf, const float* __restrict__ vec,
    const float* __restrict__ Wrbf, const float* __restrict__ so,
    const int* __restrict__ edge_src, const int* __restrict__ offs,
    const int* __restrict__ sorted,
    float* __restrict__ out_scal, float* __restrict__ out_sph, int n_nodes) {
  const int t = threadIdx.x;

  int cc[3], sel[3];
  bool act[3];
  #pragma unroll
  for (int u = 0; u < 3; ++u) {
    int j = t + 256 * u;
    int c = 0, s = 0;
    bool a = (j < 608);
    if (j < 128)      { c = j;                  s = 0; }
    else if (j < 320) { int m = (j - 128) / 3, r = (j - 128) % 3; c = 128 + m; s = 1 + r; }
    else if (j < 480) { int m = (j - 320) / 5, r = (j - 320) % 5; c = 192 + m; s = 4 + r; }
    else if (j < 608) { c = 224 + (j - 480);    s = 0; }
    cc[u] = c; sel[u] = s; act[u] = a;
  }

  float w[3][NBASIS];
  #pragma unroll
  for (int u = 0; u < 3; ++u)
    #pragma unroll
    for (int k = 0; k < NBASIS; ++k)
      w[u][k] = Wrbf[k * HID + cc[u]];

  const int nb = blockIdx.x * NPB;
  for (int nn = 0; nn < NPB; ++nn) {
    const int node = nb + nn;
    if (node >= n_nodes) break;
    float acc[3] = {0.f, 0.f, 0.f};
    const int e0 = offs[node], e1 = offs[node + 1];
    for (int ii = e0; ii < e1; ++ii) {
      const int e = sorted[ii];
      const int src = edge_src[e];
      float vx = vec[3 * (size_t)e], vy = vec[3 * (size_t)e + 1], vz = vec[3 * (size_t)e + 2];
      float rn = rsqrtf(vx * vx + vy * vy + vz * vz);
      float x = vx * rn, y = vy * rn, z = vz * rn;
      float s1x = S3f * x, s1y = S3f * y, s1z = S3f * z;
      float s20 = S15f * x * z;
      float s21 = S15f * x * y;
      float s22 = S5f * (y * y - 0.5f * (x * x + z * z));
      float s23 = S15f * y * z;
      float s24 = 0.5f * S15f * (z * z - x * x);

      float rb[NBASIS];
      #pragma unroll
      for (int k = 0; k < NBASIS; ++k) rb[k] = rbf[NBASIS * (size_t)e + k];

      const float* srow = so + (size_t)src * HID;
      #pragma unroll
      for (int u = 0; u < 3; ++u) {
        if (!act[u]) continue;
        float fw = 0.f;
        #pragma unroll
        for (int k = 0; k < NBASIS; ++k) fw += rb[k] * w[u][k];
        float f = srow[cc[u]] * fw;
        int s = sel[u];
        float factor = (s == 0) ? 1.f
                     : (s == 1) ? s1x : (s == 2) ? s1y : (s == 3) ? s1z
                     : (s == 4) ? s20 : (s == 5) ? s21 : (s == 6) ? s22
                     : (s == 7) ? s23 : s24;
        acc[u] += f * factor;
      }
    }
    #pragma unroll
    for (int u = 0; u < 3; ++u) {
      int j = t + 256 * u;
      if (j < 480) {
        float* p = out_sph + (size_t)node * SPHD + j;
        *p += acc[u];
      } else if (j < 608) {
        float* p = out_scal + (size_t)node * N_DIM + (j - 480);
        *p += acc[u];
      }
    }
  }
}

// ---------------------------------------------------------------------------
extern "C" void kernel_launch(void* const* d_in, const int* in_sizes, int n_in,
                              void* d_out, int out_size, void* d_ws, size_t ws_size,
                              hipStream_t stream) {
  const float* x_scalar = (const float*)d_in[0];
  const float* x_sph    = (const float*)d_in[1];
  const float* rbf      = (const float*)d_in[2];
  const float* vec      = (const float*)d_in[3];
  const float* W1       = (const float*)d_in[4];
  const float* b1       = (const float*)d_in[5];
  const float* W2       = (const float*)d_in[6];
  const float* b2       = (const float*)d_in[7];
  const float* Wrbf     = (const float*)d_in[8];
  const float* ln_g     = (const float*)d_in[9];
  const float* ln_b     = (const float*)d_in[10];
  const float* o3_w     = (const float*)d_in[11];
  const float* o3_b     = (const float*)d_in[12];
  const int*   edge_idx = (const int*)d_in[13];

  const int n_nodes = in_sizes[0] / N_DIM;   // 50000
  const int n_edges = in_sizes[2] / NBASIS;  // 400000

  float* out_scal = (float*)d_out;                       // [n_nodes,128]
  float* out_sph  = out_scal + (size_t)n_nodes * N_DIM;  // [n_nodes,480]

  float* ws_h  = (float*)d_ws;                           // [n_nodes,128]
  float* ws_so = ws_h + (size_t)n_nodes * N_DIM;         // [n_nodes,352]
  int* deg    = (int*)(ws_so + (size_t)n_nodes * HID);   // [n_nodes]
  int* cursor = deg + n_nodes;                           // [n_nodes]
  int* offs   = cursor + n_nodes;                        // [n_nodes+1]
  int* sorted = offs + n_nodes + 1;                      // [n_edges]

  const int* edge_dst = edge_idx;
  const int* edge_src = edge_idx + n_edges;

  // 1) node norms -> d_out (scatter base)
  node_norm_kernel<<<n_nodes, 64, 0, stream>>>(
      x_scalar, x_sph, ln_g, ln_b, o3_w, o3_b, out_scal, out_sph);

  // 2) h = silu(scalar_in @ W1 + b1)
  dim3 g1((n_nodes + 63) / 64, (N_DIM + 63) / 64);
  sgemm_kernel<true><<<g1, 256, 0, stream>>>(out_scal, W1, b1, ws_h, n_nodes, N_DIM, N_DIM);

  // 3) scalar_out = h @ W2 + b2
  dim3 g2((n_nodes + 63) / 64, (HID + 63) / 64);
  sgemm_kernel<false><<<g2, 256, 0, stream>>>(ws_h, W2, b2, ws_so, n_nodes, HID, N_DIM);

  // 4) CSR build (deg & cursor are adjacent -> single memset)
  hipMemsetAsync(deg, 0, sizeof(int) * 2 * n_nodes, stream);
  hist_kernel<<<(n_edges + 255) / 256, 256, 0, stream>>>(edge_dst, deg, n_edges);
  scan_kernel<<<1, 1024, 0, stream>>>(deg, offs, n_nodes);
  fill_kernel<<<(n_edges + 255) / 256, 256, 0, stream>>>(edge_dst, offs, cursor, sorted, n_edges);

  // 5) per-node gather (no atomics)
  gather_kernel<<<(n_nodes + NPB - 1) / NPB, 256, 0, stream>>>(
      rbf, vec, Wrbf, ws_so, edge_src, offs, sorted, out_scal, out_sph, n_nodes);
}

// Round 3
// 686.044 us; speedup vs baseline: 3.6380x; 1.3590x over previous
//
#include <hip/hip_runtime.h>
#include <hip/hip_bf16.h>

// Problem constants (from reference)
#define N_DIM   128   // NODE_DIM
#define MUL0    128
#define MUL1    64
#define MUL2    32
#define NIRR    224   // NUM_IRREPS
#define SPHD    480   // SPH_DIM
#define HID     352   // HIDDEN
#define NBASIS  20
#define EPSV    1e-5f

typedef __attribute__((ext_vector_type(8))) short bf16x8;
typedef __attribute__((ext_vector_type(4))) float f32x4;

__device__ __forceinline__ float wave_sum(float v) {
  #pragma unroll
  for (int o = 32; o > 0; o >>= 1) v += __shfl_xor(v, o, 64);
  return v;
}

__device__ __forceinline__ unsigned short f2bf(float f) {
  unsigned int u = __float_as_uint(f);
  u = (u + 0x7fff + ((u >> 16) & 1)) >> 16;  // RNE
  return (unsigned short)u;
}

// ---------------------------------------------------------------------------
// Kernel 1: per-node LayerNorm (scalar) + O3 layer norm (spherical).
// Writes results directly into d_out (they are the scatter-add base values).
// One 64-lane wave per node.
// ---------------------------------------------------------------------------
__global__ __launch_bounds__(64) void node_norm_kernel(
    const float* __restrict__ x_scalar, const float* __restrict__ x_sph,
    const float* __restrict__ ln_g, const float* __restrict__ ln_b,
    const float* __restrict__ o3_w, const float* __restrict__ o3_b,
    float* __restrict__ out_scal, float* __restrict__ out_sph) {
  const int n = blockIdx.x;
  const int l = threadIdx.x;

  const float* xs = x_scalar + (size_t)n * N_DIM;
  float a0 = xs[l], a1 = xs[l + 64];
  float mu = wave_sum(a0 + a1) * (1.f / 128.f);
  float d0 = a0 - mu, d1 = a1 - mu;
  float var = wave_sum(d0 * d0 + d1 * d1) * (1.f / 128.f);
  float sc = rsqrtf(var + EPSV);
  float* os = out_scal + (size_t)n * N_DIM;
  os[l]      = d0 * sc * ln_g[l]      + ln_b[l];
  os[l + 64] = d1 * sc * ln_g[l + 64] + ln_b[l + 64];

  const float* xp = x_sph + (size_t)n * SPHD;
  float s0 = xp[l], s1 = xp[l + 64];
  mu = wave_sum(s0 + s1) * (1.f / 128.f);
  d0 = s0 - mu; d1 = s1 - mu;
  var = wave_sum(d0 * d0 + d1 * d1) * (1.f / 128.f);
  sc = rsqrtf(var + EPSV);
  float* op = out_sph + (size_t)n * SPHD;
  op[l]      = d0 * sc * o3_w[l]      + o3_b[l];
  op[l + 64] = d1 * sc * o3_w[l + 64] + o3_b[l + 64];

  float v0 = xp[128 + l], v1 = xp[128 + 64 + l], v2 = xp[128 + 128 + l];
  float nv = wave_sum(v0 * v0 + v1 * v1 + v2 * v2) * (1.f / 192.f);
  sc = rsqrtf(nv + EPSV);
  op[128 + l]       = v0 * sc * o3_w[MUL0 + (l) / 3];
  op[128 + 64 + l]  = v1 * sc * o3_w[MUL0 + (l + 64) / 3];
  op[128 + 128 + l] = v2 * sc * o3_w[MUL0 + (l + 128) / 3];

  float t0 = xp[320 + l], t1 = xp[320 + 64 + l];
  float t2 = (l < 32) ? xp[320 + 128 + l] : 0.f;
  float nt = wave_sum(t0 * t0 + t1 * t1 + t2 * t2) * (1.f / 160.f);
  sc = rsqrtf(nt + EPSV);
  op[320 + l]      = t0 * sc * o3_w[MUL0 + MUL1 + (l) / 5];
  op[320 + 64 + l] = t1 * sc * o3_w[MUL0 + MUL1 + (l + 64) / 5];
  if (l < 32) op[320 + 128 + l] = t2 * sc * o3_w[MUL0 + MUL1 + (l + 128) / 5];
}

// ---------------------------------------------------------------------------
// Pack B (KxN fp32, K=128) into bf16 MFMA-fragment order:
// Bp[((ks*NT + nt)*64 + lane)*8 + j] = bf16(B[ks*32 + (lane>>4)*8 + j, nt*16 + (lane&15)])
// Zero-pads columns >= N.
// ---------------------------------------------------------------------------
__global__ void pack_b_kernel(const float* __restrict__ B, unsigned short* __restrict__ Bp,
                              int N, int NT) {
  int id = blockIdx.x * 256 + threadIdx.x;
  int total = 4 * NT * 64;
  if (id >= total) return;
  int lane = id & 63;
  int tmp = id >> 6;
  int nt = tmp % NT, ks = tmp / NT;
  int n = nt * 16 + (lane & 15);
  int kb = ks * 32 + (lane >> 4) * 8;
  unsigned short* o = Bp + (size_t)id * 8;
  #pragma unroll
  for (int j = 0; j < 8; ++j)
    o[j] = (n < N) ? f2bf(B[(size_t)(kb + j) * N + n]) : (unsigned short)0;
}

// ---------------------------------------------------------------------------
// bf16 MFMA GEMM: C = act(A @ B + bias), K = 128 fixed.
// Block 256 thr = 4 waves; wave handles 16 M-rows x 64 N-cols (4 n-tiles).
// A: fp32 or bf16 row-major [M,128]; B: pre-packed fragments; C: fp32 or bf16.
// Fragment layouts per m89/m91 verification:
//   A: lane holds A[m=lane&15][k = (lane>>4)*8 + j]
//   D: col = lane&15, row = (lane>>4)*4 + reg
// ---------------------------------------------------------------------------
template <bool A_BF16, bool SILU, bool OUT_BF16>
__global__ __launch_bounds__(256) void mfma_gemm_kernel(
    const void* __restrict__ Ap, const unsigned short* __restrict__ Bp,
    const float* __restrict__ bias, void* __restrict__ Cp,
    int M, int N, int NT) {
  const int lane = threadIdx.x & 63;
  const int wave = threadIdx.x >> 6;
  const int bm = blockIdx.x * 64 + wave * 16;
  const int bn = blockIdx.y * 64;
  const int q = lane >> 4;
  const int arow = min(bm + (lane & 15), M - 1);  // clamp: OOB rows give garbage, stores guarded

  f32x4 acc[4] = {};
  #pragma unroll
  for (int ks = 0; ks < 4; ++ks) {
    const int k = ks * 32 + q * 8;
    bf16x8 a;
    if (A_BF16) {
      a = *(const bf16x8*)((const unsigned short*)Ap + (size_t)arow * 128 + k);
    } else {
      const float* ap = (const float*)Ap + (size_t)arow * 128 + k;
      float4 f0 = *(const float4*)ap;
      float4 f1 = *(const float4*)(ap + 4);
      union { bf16x8 v; unsigned short s[8]; } cv;
      cv.s[0] = f2bf(f0.x); cv.s[1] = f2bf(f0.y); cv.s[2] = f2bf(f0.z); cv.s[3] = f2bf(f0.w);
      cv.s[4] = f2bf(f1.x); cv.s[5] = f2bf(f1.y); cv.s[6] = f2bf(f1.z); cv.s[7] = f2bf(f1.w);
      a = cv.v;
    }
    #pragma unroll
    for (int nt = 0; nt < 4; ++nt) {
      bf16x8 b = *(const bf16x8*)(Bp + ((size_t)(ks * NT + blockIdx.y * 4 + nt) * 64 + lane) * 8);
      acc[nt] = __builtin_amdgcn_mfma_f32_16x16x32_bf16(a, b, acc[nt], 0, 0, 0);
    }
  }
  #pragma unroll
  for (int nt = 0; nt < 4; ++nt) {
    int col = bn + nt * 16 + (lane & 15);
    if (col >= N) continue;
    float bz = bias[col];
    #pragma unroll
    for (int i = 0; i < 4; ++i) {
      int r = bm + q * 4 + i;
      if (r >= M) continue;
      float v = acc[nt][i] + bz;
      if (SILU) v = v / (1.f + __expf(-v));
      if (OUT_BF16) ((unsigned short*)Cp)[(size_t)r * N + col] = f2bf(v);
      else          ((float*)Cp)[(size_t)r * N + col] = v;
    }
  }
}

// ---------------------------------------------------------------------------
// CSR build: histogram, hierarchical exclusive scan (3 kernels), fill.
// ---------------------------------------------------------------------------
__global__ void hist_kernel(const int* __restrict__ ei, int* __restrict__ deg, int n_edges) {
  int e = blockIdx.x * blockDim.x + threadIdx.x;
  if (e < n_edges) atomicAdd(&deg[ei[e]], 1);
}

__global__ __launch_bounds__(1024) void scan_part_kernel(
    const int* __restrict__ deg, int* __restrict__ offs, int* __restrict__ bsum, int n) {
  __shared__ int wsum[16];
  const int tid = threadIdx.x, lane = tid & 63, wid = tid >> 6;
  int i = blockIdx.x * 1024 + tid;
  int v = (i < n) ? deg[i] : 0;
  int s = v;
  #pragma unroll
  for (int o = 1; o < 64; o <<= 1) {
    int t = __shfl_up(s, o, 64);
    if (lane >= o) s += t;
  }
  if (lane == 63) wsum[wid] = s;
  __syncthreads();
  if (wid == 0) {
    int ws = (lane < 16) ? wsum[lane] : 0;
    #pragma unroll
    for (int o = 1; o < 16; o <<= 1) {
      int t = __shfl_up(ws, o, 64);
      if (lane >= o) ws += t;
    }
    if (lane < 16) wsum[lane] = ws;
  }
  __syncthreads();
  int excl = ((wid == 0) ? 0 : wsum[wid - 1]) + s - v;
  if (i < n) offs[i] = excl;
  if (tid == 1023) bsum[blockIdx.x] = wsum[15];
}

__global__ __launch_bounds__(64) void scan_tops_kernel(
    const int* __restrict__ bsum, int* __restrict__ bbase, int* __restrict__ offs,
    int nb, int n) {
  const int lane = threadIdx.x;
  int v = (lane < nb) ? bsum[lane] : 0;
  int s = v;
  #pragma unroll
  for (int o = 1; o < 64; o <<= 1) {
    int t = __shfl_up(s, o, 64);
    if (lane >= o) s += t;
  }
  if (lane < nb) bbase[lane] = s - v;
  if (lane == 63) offs[n] = s;  // grand total
}

__global__ __launch_bounds__(1024) void scan_add_kernel(
    int* __restrict__ offs, const int* __restrict__ bbase, int n) {
  int i = blockIdx.x * 1024 + threadIdx.x;
  if (i < n) offs[i] += bbase[blockIdx.x];
}

__global__ void fill_kernel(const int* __restrict__ ei, const int* __restrict__ offs,
                            int* __restrict__ cursor, int* __restrict__ sorted, int n_edges) {
  int e = blockIdx.x * blockDim.x + threadIdx.x;
  if (e < n_edges) {
    int d = ei[e];
    int p = atomicAdd(&cursor[d], 1);
    sorted[offs[d] + p] = e;
  }
}

// ---------------------------------------------------------------------------
// Gather kernel, column-centric: thread t owns gate COLUMN(S) of HID=352
// (not output elements), so the 20-FMA filter dot product is computed once
// per column (352x) instead of once per output (608x). Wrbf columns live in
// registers. Classes are wave-grouped:
//   t in [0,128)   : cA=t      g0 gate      -> 1 acc (out_sph[t])
//   t in [128,192) : cA=t      MUL1 gate    -> 3 accs (out_sph[128+3m+r])
//   t in [192,224) : cA=t      MUL2 gate    -> 5 accs (out_sph[320+5m+r])
//   t in [224,256) : cA=t      msg scalar   -> 1 acc (out_scal[t-224])
//   t in [0,96)    : ALSO cB=256+t msg scalar -> 1 acc (out_scal[t+32])
// Waves 0-1 never need spherical harmonics; only waves 2-3 compute them.
// ---------------------------------------------------------------------------
#define NPB 8
#define S3f  1.7320508075688772f
#define S15f 3.872983346207417f
#define S5f  2.2360679774997896f

__global__ __launch_bounds__(256) void gather_kernel(
    const float* __restrict__ rbf, const float* __restrict__ vec,
    const float* __restrict__ Wrbf, const float* __restrict__ so,
    const int* __restrict__ edge_src, const int* __restrict__ offs,
    const int* __restrict__ sorted,
    float* __restrict__ out_scal, float* __restrict__ out_sph, int n_nodes) {
  const int t = threadIdx.x;
  const bool hasB = (t < 96);
  const bool needSH = (t >= 128 && t < 224);   // wave-uniform per 64-lane wave
  const int cA = t;
  const int cB = hasB ? (256 + t) : 0;

  float wA[NBASIS], wB[NBASIS];
  #pragma unroll
  for (int k = 0; k < NBASIS; ++k) {
    wA[k] = Wrbf[k * HID + cA];
    wB[k] = Wrbf[k * HID + cB];
  }

  const int nb = blockIdx.x * NPB;
  for (int nn = 0; nn < NPB; ++nn) {
    const int node = nb + nn;
    if (node >= n_nodes) break;
    float accA0 = 0.f, accA1 = 0.f, accA2 = 0.f, accA3 = 0.f, accA4 = 0.f;
    float accB = 0.f;
    const int e0 = offs[node], e1 = offs[node + 1];
    for (int ii = e0; ii < e1; ++ii) {
      const int e = sorted[ii];
      const int src = edge_src[e];

      // rbf row: 80 B, 16-B aligned -> 5 float4 loads
      const float4* rp = (const float4*)(rbf + (size_t)e * NBASIS);
      float4 r0 = rp[0], r1 = rp[1], r2 = rp[2], r3 = rp[3], r4 = rp[4];
      float rb[NBASIS] = {r0.x, r0.y, r0.z, r0.w, r1.x, r1.y, r1.z, r1.w,
                          r2.x, r2.y, r2.z, r2.w, r3.x, r3.y, r3.z, r3.w,
                          r4.x, r4.y, r4.z, r4.w};

      float s1x = 1.f, s1y = 1.f, s1z = 1.f, s20 = 1.f, s21 = 1.f, s22 = 1.f, s23 = 1.f, s24 = 1.f;
      if (needSH) {
        float vx = vec[3 * (size_t)e], vy = vec[3 * (size_t)e + 1], vz = vec[3 * (size_t)e + 2];
        float rn = rsqrtf(vx * vx + vy * vy + vz * vz);
        float x = vx * rn, y = vy * rn, z = vz * rn;
        s1x = S3f * x; s1y = S3f * y; s1z = S3f * z;
        s20 = S15f * x * z;
        s21 = S15f * x * y;
        s22 = S5f * (y * y - 0.5f * (x * x + z * z));
        s23 = S15f * y * z;
        s24 = 0.5f * S15f * (z * z - x * x);
      }

      float fwA = 0.f;
      #pragma unroll
      for (int k = 0; k < NBASIS; ++k) fwA += rb[k] * wA[k];
      const float* srow = so + (size_t)src * HID;
      float fA = srow[cA] * fwA;

      if (t < 128) {
        accA0 += fA;
      } else if (t < 192) {
        accA0 += fA * s1x; accA1 += fA * s1y; accA2 += fA * s1z;
      } else if (t < 224) {
        accA0 += fA * s20; accA1 += fA * s21; accA2 += fA * s22;
        accA3 += fA * s23; accA4 += fA * s24;
      } else {
        accA0 += fA;
      }

      if (hasB) {
        float fwB = 0.f;
        #pragma unroll
        for (int k = 0; k < NBASIS; ++k) fwB += rb[k] * wB[k];
        accB += srow[cB] * fwB;
      }
    }

    // write-back (base values already in d_out from node_norm_kernel)
    float* sph = out_sph + (size_t)node * SPHD;
    float* scl = out_scal + (size_t)node * N_DIM;
    if (t < 128) {
      sph[t] += accA0;
    } else if (t < 192) {
      float* p = sph + 128 + 3 * (t - 128);
      p[0] += accA0; p[1] += accA1; p[2] += accA2;
    } else if (t < 224) {
      float* p = sph + 320 + 5 * (t - 192);
      p[0] += accA0; p[1] += accA1; p[2] += accA2; p[3] += accA3; p[4] += accA4;
    } else {
      scl[t - 224] += accA0;
    }
    if (hasB) scl[t + 32] += accB;
  }
}

// ---------------------------------------------------------------------------
extern "C" void kernel_launch(void* const* d_in, const int* in_sizes, int n_in,
                              void* d_out, int out_size, void* d_ws, size_t ws_size,
                              hipStream_t stream) {
  const float* x_scalar = (const float*)d_in[0];
  const float* x_sph    = (const float*)d_in[1];
  const float* rbf      = (const float*)d_in[2];
  const float* vec      = (const float*)d_in[3];
  const float* W1       = (const float*)d_in[4];
  const float* b1       = (const float*)d_in[5];
  const float* W2       = (const float*)d_in[6];
  const float* b2       = (const float*)d_in[7];
  const float* Wrbf     = (const float*)d_in[8];
  const float* ln_g     = (const float*)d_in[9];
  const float* ln_b     = (const float*)d_in[10];
  const float* o3_w     = (const float*)d_in[11];
  const float* o3_b     = (const float*)d_in[12];
  const int*   edge_idx = (const int*)d_in[13];

  const int n_nodes = in_sizes[0] / N_DIM;   // 50000
  const int n_edges = in_sizes[2] / NBASIS;  // 400000

  float* out_scal = (float*)d_out;                       // [n_nodes,128]
  float* out_sph  = out_scal + (size_t)n_nodes * N_DIM;  // [n_nodes,480]

  // workspace layout
  float*          ws_so = (float*)d_ws;                             // [n_nodes,352] fp32
  unsigned short* h_bf  = (unsigned short*)(ws_so + (size_t)n_nodes * HID);  // [n_nodes,128] bf16
  unsigned short* bp1   = h_bf + (size_t)n_nodes * N_DIM;           // 4*8*64*8  = 16384
  unsigned short* bp2   = bp1 + 16384;                              // 4*24*64*8 = 49152
  int* deg    = (int*)(bp2 + 49152);
  int* cursor = deg + n_nodes;
  int* offs   = cursor + n_nodes;       // [n_nodes+1]
  int* bsum   = offs + n_nodes + 1;     // [64]
  int* bbase  = bsum + 64;              // [64]
  int* sorted = bbase + 64;             // [n_edges]

  const int* edge_dst = edge_idx;
  const int* edge_src = edge_idx + n_edges;

  // 1) node norms -> d_out (scatter base)
  node_norm_kernel<<<n_nodes, 64, 0, stream>>>(
      x_scalar, x_sph, ln_g, ln_b, o3_w, o3_b, out_scal, out_sph);

  // 2) pack W1/W2 into MFMA fragment order (bf16)
  pack_b_kernel<<<8, 256, 0, stream>>>(W1, bp1, N_DIM, 8);    // 4*8*64   = 2048 thr
  pack_b_kernel<<<24, 256, 0, stream>>>(W2, bp2, HID, 24);    // 4*24*64  = 6144 thr

  // 3) h = silu(scalar_in @ W1 + b1)  (A fp32, out bf16)
  {
    dim3 g((n_nodes + 63) / 64, 2);
    mfma_gemm_kernel<false, true, true><<<g, 256, 0, stream>>>(
        out_scal, bp1, b1, h_bf, n_nodes, N_DIM, 8);
  }
  // 4) scalar_out = h @ W2 + b2  (A bf16, out fp32)
  {
    dim3 g((n_nodes + 63) / 64, 6);
    mfma_gemm_kernel<true, false, false><<<g, 256, 0, stream>>>(
        h_bf, bp2, b2, ws_so, n_nodes, HID, 24);
  }

  // 5) CSR build
  hipMemsetAsync(deg, 0, sizeof(int) * 2 * n_nodes, stream);  // deg + cursor
  hist_kernel<<<(n_edges + 255) / 256, 256, 0, stream>>>(edge_dst, deg, n_edges);
  const int nb = (n_nodes + 1023) / 1024;  // 49
  scan_part_kernel<<<nb, 1024, 0, stream>>>(deg, offs, bsum, n_nodes);
  scan_tops_kernel<<<1, 64, 0, stream>>>(bsum, bbase, offs, nb, n_nodes);
  scan_add_kernel<<<nb, 1024, 0, stream>>>(offs, bbase, n_nodes);
  fill_kernel<<<(n_edges + 255) / 256, 256, 0, stream>>>(edge_dst, offs, cursor, sorted, n_edges);

  // 6) per-node column-centric gather (no atomics)
  gather_kernel<<<(n_nodes + NPB - 1) / NPB, 256, 0, stream>>>(
      rbf, vec, Wrbf, ws_so, edge_src, offs, sorted, out_scal, out_sph, n_nodes);
}